// Round 15
// baseline (28.272 us; speedup 1.0000x reference)
//
#include <hip/hip_runtime.h>
#include <math.h>

#define BB 32
#define TT 2048
#define CC 128
#define EE 256
#define LL 512
#define TYY 128
#define PP 24
#define KS 8            // K-splits per batch row (blocks per b)
#define KT 256          // t's per block
#define NST 8           // stages per block (32 t each)

// ws layout (floats):
//   pbuf  : [B*KS][P][256]   = 1572864  at 0        (j<128: sum, j>=128: cnt)
//   tpart : [B*KS*2][E]      = 131072   at 1572864
//   cemean: [E]              = 256      at 1703936
//   hbuf  : [B][L]           = 16384    at 1704192
#define WS_PBUF  0
#define WS_TPART 1572864
#define WS_CEM   1703936
#define WS_H     1704192

typedef __attribute__((ext_vector_type(8))) short bf16x8;
typedef __attribute__((ext_vector_type(4))) float f32x4;

__device__ __forceinline__ unsigned int pack_bf2(float a, float b) {
    unsigned int ua = __float_as_uint(a);
    unsigned int ub = __float_as_uint(b);
    ua = (ua + 0x7FFFu + ((ua >> 16) & 1u)) >> 16;           // RNE bf16 of a (low)
    ub = (ub + 0x7FFFu + ((ub >> 16) & 1u)) & 0xFFFF0000u;   // RNE bf16 of b (high)
    return ua | ub;
}

// ---------------------------------------------------------------------------
// K1: phase-bucket einsum via MFMA + fused sin-pool.
// R14 structure; ONE change: float4/int4 staging loads (16B/lane, G13) with
// 64B LDS rows + 16B-block XOR swizzle (write slot and read block both XOR
// (row>>2)&3 — K-blocks map 1:1, MFMA K-alignment preserved).
// grid = B*KS + 1 (257): last block computes channel-embed column mean.
// ---------------------------------------------------------------------------
__global__ __launch_bounds__(512) void k_main(const float* __restrict__ ts,
                                              const float* __restrict__ X,
                                              const int*   __restrict__ M,
                                              const float* __restrict__ tw,
                                              const float* __restrict__ tbias,
                                              const float* __restrict__ ce,
                                              float* __restrict__ pbuf,
                                              float* __restrict__ tpart,
                                              float* __restrict__ cemean) {
    __shared__ unsigned short wbuf[2][256 * 32];   // 32 KB (64B rows)
    __shared__ float s_ts[KT];
    __shared__ int   s_p[KT];

    const int tid = threadIdx.x;
    const int blk = blockIdx.x;

    if (blk == BB * KS) {                          // cemean block
        if (tid < EE) {
            float s = 0.0f;
#pragma unroll 16
            for (int c = 0; c < CC; ++c) s += ce[c * EE + tid];
            cemean[tid] = s * (1.0f / CC);
        }
        return;
    }

    const int b   = blk >> 3;
    const int ks  = blk & 7;
    const int tB  = ks * KT;

    if (tid < KT) {
        const float v = ts[b * TT + tB + tid];
        s_ts[tid] = v;
        s_p[tid] = ((int)floorf(v)) % PP;          // ts >= 0
    }

    // staging roles: thread (jq, tp) = c-quad jq*4..+3, t-pair 2tp,2tp+1
    const int jq = tid & 31;
    const int tp = tid >> 5;                       // 0..15
    const int slot = tp ^ ((jq & 3) << 2);         // 16B-block XOR swizzle
    float4 xq[2][2]; int4 mq[2][2];                // [parity][it]

    // compute roles
    const int wv   = tid >> 6;
    const int lane = tid & 63;
    const int mt   = wv & 1;
    const int jt0  = (wv >> 1) * 4;
    const int mrow = mt * 16 + (lane & 15);
    const int kg   = lane >> 4;                    // 0..3
    const int k0   = kg * 8;
    const int n16  = lane & 15;

    // sin roles
    const int se = tid & 255;
    const int sh = tid >> 8;
    const float sw = tw[se];
    const float sb = tbias[se];
    float sacc = 0.0f;

    f32x4 acc[4];
#pragma unroll
    for (int jl = 0; jl < 4; ++jl) acc[jl] = (f32x4){0.f, 0.f, 0.f, 0.f};

    auto LOADS = [&](int s) {
        const int pr = s & 1;
#pragma unroll
        for (int it = 0; it < 2; ++it) {
            const int t = tB + s * 32 + tp * 2 + it;
            const long r0 = ((long)(b * TT + t)) * CC + jq * 4;
            xq[pr][it] = *(const float4*)(X + r0);
            mq[pr][it] = *(const int4*)(M + r0);
        }
    };

    auto WRITES = [&](int s) {
        const int pr = s & 1;
        unsigned int* wb = (unsigned int*)wbuf[pr];
        const float4 x0 = xq[pr][0], x1 = xq[pr][1];
        const int4   m0 = mq[pr][0], m1 = mq[pr][1];
        wb[(4 * jq + 0) * 16 + slot] = pack_bf2(m0.x ? x0.x : 0.f, m1.x ? x1.x : 0.f);
        wb[(4 * jq + 1) * 16 + slot] = pack_bf2(m0.y ? x0.y : 0.f, m1.y ? x1.y : 0.f);
        wb[(4 * jq + 2) * 16 + slot] = pack_bf2(m0.z ? x0.z : 0.f, m1.z ? x1.z : 0.f);
        wb[(4 * jq + 3) * 16 + slot] = pack_bf2(m0.w ? x0.w : 0.f, m1.w ? x1.w : 0.f);
        wb[(128 + 4 * jq + 0) * 16 + slot] = (m0.x ? 0x3F80u : 0u) | (m1.x ? 0x3F800000u : 0u);
        wb[(128 + 4 * jq + 1) * 16 + slot] = (m0.y ? 0x3F80u : 0u) | (m1.y ? 0x3F800000u : 0u);
        wb[(128 + 4 * jq + 2) * 16 + slot] = (m0.z ? 0x3F80u : 0u) | (m1.z ? 0x3F800000u : 0u);
        wb[(128 + 4 * jq + 3) * 16 + slot] = (m0.w ? 0x3F80u : 0u) | (m1.w ? 0x3F800000u : 0u);
    };

    auto SINC = [&](int s) {
#pragma unroll
        for (int j = 0; j < 16; ++j) {
            const float v = fmaf(s_ts[s * 32 + sh * 16 + j], sw, sb);
            sacc += v + __sinf(v);
        }
    };

    LOADS(0);
    WRITES(0);
    LOADS(1);
    __syncthreads();                               // once: s_ts/s_p + wbuf[0]

    unsigned int au_all[NST][4];
#pragma unroll
    for (int s = 0; s < NST; ++s) {
        const int tb0 = s * 32 + k0;
        const int4 pA = *(const int4*)&s_p[tb0];
        const int4 pB = *(const int4*)&s_p[tb0 + 4];
        au_all[s][0] = (pA.x == mrow ? 0x3F80u : 0u) | (pA.y == mrow ? 0x3F800000u : 0u);
        au_all[s][1] = (pA.z == mrow ? 0x3F80u : 0u) | (pA.w == mrow ? 0x3F800000u : 0u);
        au_all[s][2] = (pB.x == mrow ? 0x3F80u : 0u) | (pB.y == mrow ? 0x3F800000u : 0u);
        au_all[s][3] = (pB.z == mrow ? 0x3F80u : 0u) | (pB.w == mrow ? 0x3F800000u : 0u);
    }

#pragma unroll
    for (int s = 0; s < NST; ++s) {
        if (s > 0) {
            asm volatile("s_waitcnt lgkmcnt(0)" ::: "memory");
            __builtin_amdgcn_s_barrier();          // no vmcnt drain
        }
        if (s + 2 < NST) LOADS(s + 2);
        {   // COMPUTE(s)
            union { unsigned int u[4]; bf16x8 v; } au;
            au.u[0] = au_all[s][0]; au.u[1] = au_all[s][1];
            au.u[2] = au_all[s][2]; au.u[3] = au_all[s][3];
#pragma unroll
            for (int jl = 0; jl < 4; ++jl) {
                const int jrow = (jt0 + jl) * 16 + n16;
                const int bx = kg ^ ((jrow >> 2) & 3);           // read-side swizzle
                const bf16x8 bv = *(const bf16x8*)&wbuf[s & 1][jrow * 32 + bx * 8];
                acc[jl] = __builtin_amdgcn_mfma_f32_16x16x32_bf16(au.v, bv, acc[jl], 0, 0, 0);
            }
        }
        SINC(s);
        if (s + 1 < NST) WRITES(s + 1);
    }

    tpart[((b * KS + ks) * 2 + sh) * EE + se] = sacc;

    float* pbb = pbuf + ((long)blk) * PP * 256;
#pragma unroll
    for (int jl = 0; jl < 4; ++jl) {
#pragma unroll
        for (int r = 0; r < 4; ++r) {
            const int p = mt * 16 + kg * 4 + r;
            if (p < PP)
                pbb[p * 256 + (jt0 + jl) * 16 + n16] = acc[jl][r];
        }
    }
}

// ---------------------------------------------------------------------------
// K2: hidden layer, w1 PARTITIONED. grid = B*8 (256), block = 256.
// ---------------------------------------------------------------------------
__global__ __launch_bounds__(256) void k_hid(const float* __restrict__ tpart,
                                             const float* __restrict__ cemean,
                                             const float* __restrict__ w1,
                                             const float* __restrict__ b1,
                                             float* __restrict__ hbuf) {
    __shared__ float s_pool[EE];
    __shared__ float s_hp[256];
    const int b = blockIdx.x >> 3;
    const int q = blockIdx.x & 7;
    const int tid = threadIdx.x;

    {
        float sp = 0.0f;
#pragma unroll
        for (int k = 0; k < KS * 2; ++k) sp += tpart[(b * KS * 2 + k) * EE + tid];
        s_pool[tid] = sp * (1.0f / TT) + cemean[tid];
    }
    __syncthreads();

    const int l = q * 64 + (tid & 63);
    const int eq = tid >> 6;                       // 0..3, 64 e's each
    float ha = 0.0f;
#pragma unroll 16
    for (int e = eq * 64; e < eq * 64 + 64; ++e)
        ha = fmaf(s_pool[e], w1[e * LL + l], ha);
    s_hp[tid] = ha;
    __syncthreads();
    if (tid < 64)
        hbuf[b * LL + q * 64 + tid] =
            fmaxf(b1[q * 64 + tid] + s_hp[tid] + s_hp[tid + 64]
                  + s_hp[tid + 128] + s_hp[tid + 192], 0.0f);
}

// ---------------------------------------------------------------------------
// K3: output layer, w2 PARTITIONED + own cbase c-slice from pbuf + scatter.
// grid = B*8 (256), block = 256. Block (b,co): c in [co*16, +16).
// ---------------------------------------------------------------------------
__global__ __launch_bounds__(256) void k_out(const float* __restrict__ hbuf,
                                             const float* __restrict__ w2,
                                             const float* __restrict__ b2,
                                             const float* __restrict__ pbuf,
                                             const float* __restrict__ yt,
                                             float* __restrict__ out) {
    __shared__ float s_h[LL];
    __shared__ float s_yp[256];
    __shared__ float s_y[16];
    __shared__ float s_cb[PP * 16];
    __shared__ int   s_ph[TYY];
    const int b  = blockIdx.x >> 3;
    const int co = blockIdx.x & 7;
    const int tid = threadIdx.x;

    for (int i = tid; i < LL; i += 256) s_h[i] = hbuf[b * LL + i];
    if (tid < TYY) {
        const float v = yt[b * TYY + tid];
        int p = ((int)floorf(v)) % PP; if (p < 0) p += PP;
        s_ph[tid] = p;
    }
    __syncthreads();

    {
        const int c16 = tid & 15;
        const int lg = tid >> 4;
        float y = 0.0f;
#pragma unroll 8
        for (int l = lg * 32; l < lg * 32 + 32; ++l)
            y = fmaf(s_h[l], w2[l * CC + co * 16 + c16], y);
        s_yp[tid] = y;
    }
    for (int i = tid; i < PP * 16; i += 256) {
        const int p = i >> 4;
        const int c = co * 16 + (i & 15);
        float s = 0.0f, n = 0.0f;
#pragma unroll
        for (int k = 0; k < KS; ++k) {
            const float* pb = pbuf + ((long)(b * KS + k)) * PP * 256 + p * 256;
            s += pb[c];
            n += pb[128 + c];
        }
        s_cb[i] = s / fmaxf(n, 1.0f);
    }
    __syncthreads();
    if (tid < 16) {
        float yy = b2[co * 16 + tid];
#pragma unroll
        for (int g = 0; g < 16; ++g) yy += s_yp[tid + 16 * g];
        s_y[tid] = yy;
    }
    __syncthreads();

    for (int i = tid; i < TYY * 16; i += 256) {
        const int ty = i >> 4;
        const int ci = i & 15;
        out[((long)(b * TYY + ty)) * CC + co * 16 + ci] =
            s_y[ci] + s_cb[s_ph[ty] * 16 + ci];
    }
}

extern "C" void kernel_launch(void* const* d_in, const int* in_sizes, int n_in,
                              void* d_out, int out_size, void* d_ws, size_t ws_size,
                              hipStream_t stream) {
    const float* ts   = (const float*)d_in[0];
    const float* X    = (const float*)d_in[1];
    const int*   M    = (const int*)  d_in[2];
    const float* yt   = (const float*)d_in[3];
    const float* tw   = (const float*)d_in[4];
    const float* tb   = (const float*)d_in[5];
    const float* ce   = (const float*)d_in[6];
    const float* w1   = (const float*)d_in[7];
    const float* b1   = (const float*)d_in[8];
    const float* w2   = (const float*)d_in[9];
    const float* b2   = (const float*)d_in[10];
    float* out = (float*)d_out;

    float* ws     = (float*)d_ws;
    float* pbuf   = ws + WS_PBUF;
    float* tpart  = ws + WS_TPART;
    float* cemean = ws + WS_CEM;
    float* hbuf   = ws + WS_H;

    k_main<<<BB * KS + 1, 512, 0, stream>>>(ts, X, M, tw, tb, ce, pbuf, tpart, cemean);
    k_hid<<<BB * 8, 256, 0, stream>>>(tpart, cemean, w1, b1, hbuf);
    k_out<<<BB * 8, 256, 0, stream>>>(hbuf, w2, b2, pbuf, yt, out);
}